// Round 10
// baseline (1182.716 us; speedup 1.0000x reference)
//
#include <hip/hip_runtime.h>

// TFLite STFT: B=16, T=480000, frame_len=fft_len=800, step=200
// -> num_frames=2397, bins=401.
// Output-layout hedge: harness passes out_size; dispatch on it.
//   out_size == NB*NFRAMES*NBINS     -> real part only (npz-size evidence)
//   out_size == 2*NB*NFRAMES*NBINS   -> complex64 interleaved (re,im) pairs
// Either way we write exactly out_size floats -> no OOB, no abort.
// Trig computed inline with exact (k*l)%800 reduction + hardware __sincosf.

#define NB      16
#define NT      480000
#define FLEN    800
#define STEP    200
#define NFRAMES 2397
#define NBINS   401

#define BF   32    // frames per block tile
#define BK   32    // bins per block tile
#define LCH  100   // l-chunk length
#define LPAD 108   // padded trig row stride: 432B, 16B-aligned, bank-stride 12 -> 2-way max (free)

template <bool COMPLEX>
__global__ __launch_bounds__(256)
void stft_f32_kernel(const float* __restrict__ sig,
                     const float* __restrict__ win,
                     float* __restrict__ out) {
    __shared__ float s_sig[(BF - 1) * STEP + LCH];   // 6300 floats = 25.2 KB
    __shared__ float s_cw[BK][LPAD];                 // 13.8 KB
    __shared__ float s_sw[COMPLEX ? BK : 1][LPAD];   // 13.8 KB when COMPLEX

    const int tid = threadIdx.x;
    const int k0 = blockIdx.x * BK;
    const int f0 = blockIdx.y * BF;
    const int b  = blockIdx.z;

    const int kk = tid & 15;   // bins kk, kk+16
    const int ff = tid >> 4;   // frames ff, ff+16

    float r00 = 0.f, r01 = 0.f, r10 = 0.f, r11 = 0.f;
    float i00 = 0.f, i01 = 0.f, i10 = 0.f, i11 = 0.f;

    const float* sigb = sig + (long long)b * NT;

    for (int l0 = 0; l0 < FLEN; l0 += LCH) {
        // stage signal chunk: samples f0*STEP + l0 + [0, 6300)
        for (int i = tid; i < (BF - 1) * STEP + LCH; i += 256) {
            int gs = f0 * STEP + l0 + i;
            s_sig[i] = (gs < NT) ? sigb[gs] : 0.0f;
        }
        // stage window-folded trig chunk: BK bins x LCH, computed inline
        for (int i = tid; i < BK * LCH; i += 256) {
            int kx = i / LCH;
            int dl = i - kx * LCH;
            int k  = k0 + kx;
            int l  = l0 + dl;
            float c = 0.f, s = 0.f;
            if (k < NBINS) {
                int m = (k * l) % FLEN;               // exact reduction
                float ang = (float)m * -0.00785398163397448279f; // -2*pi/800
                float w = win[l];
                if constexpr (COMPLEX) {
                    float sv, cv;
                    __sincosf(ang, &sv, &cv);
                    c = cv * w; s = sv * w;
                } else {
                    c = __cosf(ang) * w;
                }
            }
            s_cw[kx][dl] = c;
            if constexpr (COMPLEX) s_sw[kx][dl] = s;
        }
        __syncthreads();

        for (int dl = 0; dl < LCH; dl += 4) {
            float4 a0 = *(const float4*)&s_sig[ff * STEP + dl];
            float4 a1 = *(const float4*)&s_sig[(ff + 16) * STEP + dl];
            float4 c0 = *(const float4*)&s_cw[kk][dl];
            float4 c1 = *(const float4*)&s_cw[kk + 16][dl];

            r00 = fmaf(a0.x, c0.x, r00); r00 = fmaf(a0.y, c0.y, r00);
            r00 = fmaf(a0.z, c0.z, r00); r00 = fmaf(a0.w, c0.w, r00);
            r01 = fmaf(a0.x, c1.x, r01); r01 = fmaf(a0.y, c1.y, r01);
            r01 = fmaf(a0.z, c1.z, r01); r01 = fmaf(a0.w, c1.w, r01);
            r10 = fmaf(a1.x, c0.x, r10); r10 = fmaf(a1.y, c0.y, r10);
            r10 = fmaf(a1.z, c0.z, r10); r10 = fmaf(a1.w, c0.w, r10);
            r11 = fmaf(a1.x, c1.x, r11); r11 = fmaf(a1.y, c1.y, r11);
            r11 = fmaf(a1.z, c1.z, r11); r11 = fmaf(a1.w, c1.w, r11);

            if constexpr (COMPLEX) {
                float4 n0 = *(const float4*)&s_sw[kk][dl];
                float4 n1 = *(const float4*)&s_sw[kk + 16][dl];
                i00 = fmaf(a0.x, n0.x, i00); i00 = fmaf(a0.y, n0.y, i00);
                i00 = fmaf(a0.z, n0.z, i00); i00 = fmaf(a0.w, n0.w, i00);
                i01 = fmaf(a0.x, n1.x, i01); i01 = fmaf(a0.y, n1.y, i01);
                i01 = fmaf(a0.z, n1.z, i01); i01 = fmaf(a0.w, n1.w, i01);
                i10 = fmaf(a1.x, n0.x, i10); i10 = fmaf(a1.y, n0.y, i10);
                i10 = fmaf(a1.z, n0.z, i10); i10 = fmaf(a1.w, n0.w, i10);
                i11 = fmaf(a1.x, n1.x, i11); i11 = fmaf(a1.y, n1.y, i11);
                i11 = fmaf(a1.z, n1.z, i11); i11 = fmaf(a1.w, n1.w, i11);
            }
        }
        __syncthreads();
    }

    const long long ob = (long long)b * NFRAMES;
    #define WRITE_ONE(F, K, RV, IV)                                        \
        {                                                                  \
            int f = (F), k = (K);                                          \
            if (f < NFRAMES && k < NBINS) {                                \
                long long o = (ob + f) * (long long)NBINS + k;             \
                if constexpr (COMPLEX) {                                   \
                    out[o * 2] = (RV); out[o * 2 + 1] = (IV);              \
                } else {                                                   \
                    out[o] = (RV);                                         \
                }                                                          \
            }                                                              \
        }
    WRITE_ONE(f0 + ff,      k0 + kk,      r00, i00)
    WRITE_ONE(f0 + ff,      k0 + kk + 16, r01, i01)
    WRITE_ONE(f0 + ff + 16, k0 + kk,      r10, i10)
    WRITE_ONE(f0 + ff + 16, k0 + kk + 16, r11, i11)
    #undef WRITE_ONE
}

extern "C" void kernel_launch(void* const* d_in, const int* in_sizes, int n_in,
                              void* d_out, int out_size, void* d_ws, size_t ws_size,
                              hipStream_t stream) {
    const float* sig = (const float*)d_in[0];
    const float* win = (const float*)d_in[1];

    dim3 grid((NBINS + BK - 1) / BK, (NFRAMES + BF - 1) / BF, NB);
    const long long n_complex = (long long)NB * NFRAMES * NBINS;
    if ((long long)out_size >= 2 * n_complex) {
        stft_f32_kernel<true><<<grid, dim3(256), 0, stream>>>(sig, win, (float*)d_out);
    } else {
        stft_f32_kernel<false><<<grid, dim3(256), 0, stream>>>(sig, win, (float*)d_out);
    }
}

// Round 11
// 186.429 us; speedup vs baseline: 6.3441x; 6.3441x over previous
//
#include <hip/hip_runtime.h>

// TFLite STFT: B=16, T=480000, frame_len=fft_len=800, step=200
// -> num_frames=2397, bins=401. Output CONFIRMED (round 10): real part only,
// out[(b*2397+f)*401+k], out_size = 15,379,152 floats.
//
// MFMA formulation: C[f,k] = sum_l sig[b,f*200+l] * (cos(-2pi*k*l/800)*win[l])
// = bf16 GEMM, K=800, via mfma_f32_16x16x32_bf16.
// W is precomputed in B-fragment-linear layout (coalesced frag loads from L2);
// signal pre-converted to bf16. No LDS. Fallback to proven fp32 kernel if ws
// is too small.

#define NB      16
#define NT      480000
#define FLEN    800
#define STEP    200
#define NFRAMES 2397
#define NBINS   401

#define NKT     28                      // k-tiles of 16 bins (448 >= 401+pad to 64-multiple blocks)
#define NKS     25                      // K-chunks of 32 (800/32)
#define SIG_OFF (1u << 20)              // sig bf16 at +1MB in ws
#define WS_NEED (SIG_OFF + (size_t)NB * NT * 2)

typedef __bf16 bf16x8 __attribute__((ext_vector_type(8)));
typedef __bf16 bf16x4 __attribute__((ext_vector_type(4)));
typedef float  f32x4  __attribute__((ext_vector_type(4)));

// ---- prep 1: fp32 signal -> bf16 ----
__global__ __launch_bounds__(256)
void convert_sig_kernel(const float* __restrict__ in, __bf16* __restrict__ outb) {
    size_t i = (size_t)blockIdx.x * 256 + threadIdx.x;
    if (i >= (size_t)NB * NT / 4) return;
    float4 v = ((const float4*)in)[i];
    bf16x4 o;
    o[0] = (__bf16)v.x; o[1] = (__bf16)v.y; o[2] = (__bf16)v.z; o[3] = (__bf16)v.w;
    ((bf16x4*)outb)[i] = o;
}

// ---- prep 2: W in B-fragment-linear layout ----
// frag index = ks*NKT + kt; lane l: col(bin) = kt*16 + (l&15),
// element j: l_global = ks*32 + (l>>4)*8 + j.
__global__ __launch_bounds__(256)
void build_wfrag_kernel(const float* __restrict__ win, __bf16* __restrict__ w) {
    int t = blockIdx.x * 256 + threadIdx.x;
    if (t >= NKS * NKT * 64) return;
    int lane = t & 63, frag = t >> 6;
    int kt = frag % NKT, ks = frag / NKT;
    int bin = kt * 16 + (lane & 15);
    int lbase = ks * 32 + (lane >> 4) * 8;
    bf16x8 o;
    #pragma unroll
    for (int j = 0; j < 8; ++j) {
        int l = lbase + j;
        int m = (bin * l) % FLEN;                       // exact reduction
        float c = cosf((float)m * -0.00785398163397448279f) * win[l];
        o[j] = (__bf16)c;
    }
    ((bf16x8*)w)[t] = o;
}

// ---- main: bf16 MFMA GEMM ----
// block = 4 waves stacked in f: 256 frames x 64 bins. wave tile 64f x 64k.
__global__ __launch_bounds__(256)
void stft_mfma_kernel(const __bf16* __restrict__ sigb,
                      const __bf16* __restrict__ w,
                      float* __restrict__ out) {
    const int lane = threadIdx.x & 63;
    const int wid  = threadIdx.x >> 6;
    const int b    = blockIdx.z;
    const int f0   = blockIdx.y * 256 + wid * 64;
    const int kt0  = blockIdx.x * 4;
    const int r    = lane & 15;      // A row / B col / C col within 16-tile
    const int h    = lane >> 4;      // K-half group 0..3

    const __bf16* sb = sigb + (size_t)b * NT;
    const bf16x8* wf = (const bf16x8*)w;

    // A-frag base pointers per m-subtile (16B units; +4 per K-step of 32 elems)
    const bf16x8* ap0; const bf16x8* ap1; const bf16x8* ap2; const bf16x8* ap3;
    {
        int r0 = f0 + 0  + r; if (r0 > NFRAMES - 1) r0 = NFRAMES - 1;
        int r1 = f0 + 16 + r; if (r1 > NFRAMES - 1) r1 = NFRAMES - 1;
        int r2 = f0 + 32 + r; if (r2 > NFRAMES - 1) r2 = NFRAMES - 1;
        int r3 = f0 + 48 + r; if (r3 > NFRAMES - 1) r3 = NFRAMES - 1;
        ap0 = (const bf16x8*)(sb + (size_t)r0 * STEP) + h;   // (r*400 + h*16) bytes: 16B aligned
        ap1 = (const bf16x8*)(sb + (size_t)r1 * STEP) + h;
        ap2 = (const bf16x8*)(sb + (size_t)r2 * STEP) + h;
        ap3 = (const bf16x8*)(sb + (size_t)r3 * STEP) + h;
    }

    f32x4 acc[4][4];
    #pragma unroll
    for (int m = 0; m < 4; ++m)
        #pragma unroll
        for (int n = 0; n < 4; ++n)
            acc[m][n] = (f32x4){0.f, 0.f, 0.f, 0.f};

    for (int ks = 0; ks < NKS; ++ks) {
        bf16x8 a0 = ap0[ks * 4];
        bf16x8 a1 = ap1[ks * 4];
        bf16x8 a2 = ap2[ks * 4];
        bf16x8 a3 = ap3[ks * 4];
        bf16x8 b0 = wf[(ks * NKT + kt0 + 0) * 64 + lane];
        bf16x8 b1 = wf[(ks * NKT + kt0 + 1) * 64 + lane];
        bf16x8 b2 = wf[(ks * NKT + kt0 + 2) * 64 + lane];
        bf16x8 b3 = wf[(ks * NKT + kt0 + 3) * 64 + lane];

        #define MM(AM, I)                                                            \
            acc[I][0] = __builtin_amdgcn_mfma_f32_16x16x32_bf16(AM, b0, acc[I][0], 0, 0, 0); \
            acc[I][1] = __builtin_amdgcn_mfma_f32_16x16x32_bf16(AM, b1, acc[I][1], 0, 0, 0); \
            acc[I][2] = __builtin_amdgcn_mfma_f32_16x16x32_bf16(AM, b2, acc[I][2], 0, 0, 0); \
            acc[I][3] = __builtin_amdgcn_mfma_f32_16x16x32_bf16(AM, b3, acc[I][3], 0, 0, 0);
        MM(a0, 0) MM(a1, 1) MM(a2, 2) MM(a3, 3)
        #undef MM
    }

    // C/D layout: col = lane&15 (bin), row = (lane>>4)*4 + reg (frame)
    const size_t ob = (size_t)b * NFRAMES;
    #pragma unroll
    for (int m = 0; m < 4; ++m) {
        int fbase = f0 + m * 16 + h * 4;
        #pragma unroll
        for (int n = 0; n < 4; ++n) {
            int k = blockIdx.x * 64 + n * 16 + r;
            if (k < NBINS) {
                #pragma unroll
                for (int reg = 0; reg < 4; ++reg) {
                    int f = fbase + reg;
                    if (f < NFRAMES)
                        out[(ob + f) * NBINS + k] = acc[m][n][reg];
                }
            }
        }
    }
}

// ---- fp32 fallback (proven round 10): used only if ws too small ----
#define BFT 32
#define BKT 32
#define LCH 100
#define LPAD 108
__global__ __launch_bounds__(256)
void stft_f32_kernel(const float* __restrict__ sig, const float* __restrict__ win,
                     float* __restrict__ out) {
    __shared__ float s_sig[(BFT - 1) * STEP + LCH];
    __shared__ float s_cw[BKT][LPAD];
    const int tid = threadIdx.x;
    const int k0 = blockIdx.x * BKT, f0 = blockIdx.y * BFT, b = blockIdx.z;
    const int kk = tid & 15, ff = tid >> 4;
    float r00 = 0.f, r01 = 0.f, r10 = 0.f, r11 = 0.f;
    const float* sigb = sig + (size_t)b * NT;
    for (int l0 = 0; l0 < FLEN; l0 += LCH) {
        for (int i = tid; i < (BFT - 1) * STEP + LCH; i += 256) {
            int gs = f0 * STEP + l0 + i;
            s_sig[i] = (gs < NT) ? sigb[gs] : 0.0f;
        }
        for (int i = tid; i < BKT * LCH; i += 256) {
            int kx = i / LCH, dl = i - kx * LCH, k = k0 + kx, l = l0 + dl;
            float c = 0.f;
            if (k < NBINS) {
                int m = (k * l) % FLEN;
                c = __cosf((float)m * -0.00785398163397448279f) * win[l];
            }
            s_cw[kx][dl] = c;
        }
        __syncthreads();
        for (int dl = 0; dl < LCH; dl += 4) {
            float4 a0 = *(const float4*)&s_sig[ff * STEP + dl];
            float4 a1 = *(const float4*)&s_sig[(ff + 16) * STEP + dl];
            float4 c0 = *(const float4*)&s_cw[kk][dl];
            float4 c1 = *(const float4*)&s_cw[kk + 16][dl];
            r00 = fmaf(a0.x, c0.x, r00); r00 = fmaf(a0.y, c0.y, r00);
            r00 = fmaf(a0.z, c0.z, r00); r00 = fmaf(a0.w, c0.w, r00);
            r01 = fmaf(a0.x, c1.x, r01); r01 = fmaf(a0.y, c1.y, r01);
            r01 = fmaf(a0.z, c1.z, r01); r01 = fmaf(a0.w, c1.w, r01);
            r10 = fmaf(a1.x, c0.x, r10); r10 = fmaf(a1.y, c0.y, r10);
            r10 = fmaf(a1.z, c0.z, r10); r10 = fmaf(a1.w, c0.w, r10);
            r11 = fmaf(a1.x, c1.x, r11); r11 = fmaf(a1.y, c1.y, r11);
            r11 = fmaf(a1.z, c1.z, r11); r11 = fmaf(a1.w, c1.w, r11);
        }
        __syncthreads();
    }
    const size_t ob = (size_t)b * NFRAMES;
    { int f = f0 + ff,      k = k0 + kk;      if (f < NFRAMES && k < NBINS) out[(ob + f) * NBINS + k] = r00; }
    { int f = f0 + ff,      k = k0 + kk + 16; if (f < NFRAMES && k < NBINS) out[(ob + f) * NBINS + k] = r01; }
    { int f = f0 + ff + 16, k = k0 + kk;      if (f < NFRAMES && k < NBINS) out[(ob + f) * NBINS + k] = r10; }
    { int f = f0 + ff + 16, k = k0 + kk + 16; if (f < NFRAMES && k < NBINS) out[(ob + f) * NBINS + k] = r11; }
}

extern "C" void kernel_launch(void* const* d_in, const int* in_sizes, int n_in,
                              void* d_out, int out_size, void* d_ws, size_t ws_size,
                              hipStream_t stream) {
    const float* sig = (const float*)d_in[0];
    const float* win = (const float*)d_in[1];
    float* out = (float*)d_out;

    if (ws_size >= WS_NEED) {
        __bf16* wfr    = (__bf16*)d_ws;
        __bf16* sigb16 = (__bf16*)((char*)d_ws + SIG_OFF);
        convert_sig_kernel<<<dim3((NB * NT / 4 + 255) / 256), dim3(256), 0, stream>>>(sig, sigb16);
        build_wfrag_kernel<<<dim3((NKS * NKT * 64 + 255) / 256), dim3(256), 0, stream>>>(win, wfr);
        dim3 grid((NBINS + 63) / 64, (NFRAMES + 255) / 256, NB);   // 7 x 10 x 16
        stft_mfma_kernel<<<grid, dim3(256), 0, stream>>>(sigb16, wfr, out);
    } else {
        dim3 grid((NBINS + BKT - 1) / BKT, (NFRAMES + BFT - 1) / BFT, NB);
        stft_f32_kernel<<<grid, dim3(256), 0, stream>>>(sig, win, out);
    }
}

// Round 12
// 154.993 us; speedup vs baseline: 7.6308x; 1.2028x over previous
//
#include <hip/hip_runtime.h>

// TFLite STFT as bf16 MFMA GEMM. Output confirmed: real part only,
// out[(b*2397+f)*401+k], 15,379,152 floats.
// Round 12: XCD-aware block swizzle (7 k-column blocks of each (y,z) group
// -> same XCD, A re-reads become L2 hits; round-11 FETCH was 230MB vs 16MB
// compulsory) + 2x parallelism (wave tile 32f x 64k, 2128 blocks).

#define NB      16
#define NT      480000
#define FLEN    800
#define STEP    200
#define NFRAMES 2397
#define NBINS   401

#define NKT     28                      // k-tiles of 16 bins (448 total)
#define NKS     25                      // K-chunks of 32 (800/32)
#define GX      7                       // k-column blocks (64 bins each)
#define GY      19                      // frame blocks (128 frames each)
#define NWG     (GX * GY * NB)          // 2128 = 8 * 266
#define PER_XCD (NWG / 8)               // 266
#define SIG_OFF (1u << 20)              // sig bf16 at +1MB in ws
#define WS_NEED (SIG_OFF + (size_t)NB * NT * 2)

typedef __bf16 bf16x8 __attribute__((ext_vector_type(8)));
typedef __bf16 bf16x4 __attribute__((ext_vector_type(4)));
typedef float  f32x4  __attribute__((ext_vector_type(4)));

// ---- prep 1: fp32 signal -> bf16 ----
__global__ __launch_bounds__(256)
void convert_sig_kernel(const float* __restrict__ in, __bf16* __restrict__ outb) {
    size_t i = (size_t)blockIdx.x * 256 + threadIdx.x;
    if (i >= (size_t)NB * NT / 4) return;
    float4 v = ((const float4*)in)[i];
    bf16x4 o;
    o[0] = (__bf16)v.x; o[1] = (__bf16)v.y; o[2] = (__bf16)v.z; o[3] = (__bf16)v.w;
    ((bf16x4*)outb)[i] = o;
}

// ---- prep 2: W in B-fragment-linear layout ----
// frag index = ks*NKT + kt; lane l: col(bin) = kt*16 + (l&15),
// element j: l_global = ks*32 + (l>>4)*8 + j.
__global__ __launch_bounds__(256)
void build_wfrag_kernel(const float* __restrict__ win, __bf16* __restrict__ w) {
    int t = blockIdx.x * 256 + threadIdx.x;
    if (t >= NKS * NKT * 64) return;
    int lane = t & 63, frag = t >> 6;
    int kt = frag % NKT, ks = frag / NKT;
    int bin = kt * 16 + (lane & 15);
    int lbase = ks * 32 + (lane >> 4) * 8;
    bf16x8 o;
    #pragma unroll
    for (int j = 0; j < 8; ++j) {
        int l = lbase + j;
        int m = (bin * l) % FLEN;                       // exact reduction
        float c = cosf((float)m * -0.00785398163397448279f) * win[l];
        o[j] = (__bf16)c;
    }
    ((bf16x8*)w)[t] = o;
}

// ---- main: bf16 MFMA GEMM, wave tile 32f x 64k, block 128f x 64k ----
__global__ __launch_bounds__(256)
void stft_mfma_kernel(const __bf16* __restrict__ sigb,
                      const __bf16* __restrict__ w,
                      float* __restrict__ out) {
    // XCD-aware swizzle: dispatch id D runs on XCD D%8. Give each XCD a
    // contiguous x-major chunk so all GX k-column blocks of a (y,b) group
    // share one XCD's L2.
    const int D = blockIdx.x + GX * (blockIdx.y + GY * blockIdx.z);
    const int P = (D % 8) * PER_XCD + (D / 8);
    const int x  = P % GX;
    const int yz = P / GX;
    const int y  = yz % GY;
    const int b  = yz / GY;

    const int lane = threadIdx.x & 63;
    const int wid  = threadIdx.x >> 6;
    const int f0   = y * 128 + wid * 32;
    const int kt0  = x * 4;
    const int r    = lane & 15;      // A row / C col within 16-tile
    const int h    = lane >> 4;      // K-half group 0..3

    const __bf16* sb = sigb + (size_t)b * NT;
    const bf16x8* wf = (const bf16x8*)w;

    const bf16x8* ap0; const bf16x8* ap1;
    {
        int r0 = f0 + 0  + r; if (r0 > NFRAMES - 1) r0 = NFRAMES - 1;
        int r1 = f0 + 16 + r; if (r1 > NFRAMES - 1) r1 = NFRAMES - 1;
        ap0 = (const bf16x8*)(sb + (size_t)r0 * STEP) + h;   // 16B aligned
        ap1 = (const bf16x8*)(sb + (size_t)r1 * STEP) + h;
    }

    f32x4 acc[2][4];
    #pragma unroll
    for (int m = 0; m < 2; ++m)
        #pragma unroll
        for (int n = 0; n < 4; ++n)
            acc[m][n] = (f32x4){0.f, 0.f, 0.f, 0.f};

    for (int ks = 0; ks < NKS; ++ks) {
        bf16x8 a0 = ap0[ks * 4];
        bf16x8 a1 = ap1[ks * 4];
        bf16x8 b0 = wf[(ks * NKT + kt0 + 0) * 64 + lane];
        bf16x8 b1 = wf[(ks * NKT + kt0 + 1) * 64 + lane];
        bf16x8 b2 = wf[(ks * NKT + kt0 + 2) * 64 + lane];
        bf16x8 b3 = wf[(ks * NKT + kt0 + 3) * 64 + lane];

        #define MM(AM, I)                                                            \
            acc[I][0] = __builtin_amdgcn_mfma_f32_16x16x32_bf16(AM, b0, acc[I][0], 0, 0, 0); \
            acc[I][1] = __builtin_amdgcn_mfma_f32_16x16x32_bf16(AM, b1, acc[I][1], 0, 0, 0); \
            acc[I][2] = __builtin_amdgcn_mfma_f32_16x16x32_bf16(AM, b2, acc[I][2], 0, 0, 0); \
            acc[I][3] = __builtin_amdgcn_mfma_f32_16x16x32_bf16(AM, b3, acc[I][3], 0, 0, 0);
        MM(a0, 0) MM(a1, 1)
        #undef MM
    }

    // C/D layout: col = lane&15 (bin), row = (lane>>4)*4 + reg (frame)
    const size_t ob = (size_t)b * NFRAMES;
    #pragma unroll
    for (int m = 0; m < 2; ++m) {
        int fbase = f0 + m * 16 + h * 4;
        #pragma unroll
        for (int n = 0; n < 4; ++n) {
            int k = x * 64 + n * 16 + r;
            if (k < NBINS) {
                #pragma unroll
                for (int reg = 0; reg < 4; ++reg) {
                    int f = fbase + reg;
                    if (f < NFRAMES)
                        out[(ob + f) * NBINS + k] = acc[m][n][reg];
                }
            }
        }
    }
}

// ---- fp32 fallback (proven round 10): used only if ws too small ----
#define BFT 32
#define BKT 32
#define LCH 100
#define LPAD 108
__global__ __launch_bounds__(256)
void stft_f32_kernel(const float* __restrict__ sig, const float* __restrict__ win,
                     float* __restrict__ out) {
    __shared__ float s_sig[(BFT - 1) * STEP + LCH];
    __shared__ float s_cw[BKT][LPAD];
    const int tid = threadIdx.x;
    const int k0 = blockIdx.x * BKT, f0 = blockIdx.y * BFT, b = blockIdx.z;
    const int kk = tid & 15, ff = tid >> 4;
    float r00 = 0.f, r01 = 0.f, r10 = 0.f, r11 = 0.f;
    const float* sigb = sig + (size_t)b * NT;
    for (int l0 = 0; l0 < FLEN; l0 += LCH) {
        for (int i = tid; i < (BFT - 1) * STEP + LCH; i += 256) {
            int gs = f0 * STEP + l0 + i;
            s_sig[i] = (gs < NT) ? sigb[gs] : 0.0f;
        }
        for (int i = tid; i < BKT * LCH; i += 256) {
            int kx = i / LCH, dl = i - kx * LCH, k = k0 + kx, l = l0 + dl;
            float c = 0.f;
            if (k < NBINS) {
                int m = (k * l) % FLEN;
                c = __cosf((float)m * -0.00785398163397448279f) * win[l];
            }
            s_cw[kx][dl] = c;
        }
        __syncthreads();
        for (int dl = 0; dl < LCH; dl += 4) {
            float4 a0 = *(const float4*)&s_sig[ff * STEP + dl];
            float4 a1 = *(const float4*)&s_sig[(ff + 16) * STEP + dl];
            float4 c0 = *(const float4*)&s_cw[kk][dl];
            float4 c1 = *(const float4*)&s_cw[kk + 16][dl];
            r00 = fmaf(a0.x, c0.x, r00); r00 = fmaf(a0.y, c0.y, r00);
            r00 = fmaf(a0.z, c0.z, r00); r00 = fmaf(a0.w, c0.w, r00);
            r01 = fmaf(a0.x, c1.x, r01); r01 = fmaf(a0.y, c1.y, r01);
            r01 = fmaf(a0.z, c1.z, r01); r01 = fmaf(a0.w, c1.w, r01);
            r10 = fmaf(a1.x, c0.x, r10); r10 = fmaf(a1.y, c0.y, r10);
            r10 = fmaf(a1.z, c0.z, r10); r10 = fmaf(a1.w, c0.w, r10);
            r11 = fmaf(a1.x, c1.x, r11); r11 = fmaf(a1.y, c1.y, r11);
            r11 = fmaf(a1.z, c1.z, r11); r11 = fmaf(a1.w, c1.w, r11);
        }
        __syncthreads();
    }
    const size_t ob = (size_t)b * NFRAMES;
    { int f = f0 + ff,      k = k0 + kk;      if (f < NFRAMES && k < NBINS) out[(ob + f) * NBINS + k] = r00; }
    { int f = f0 + ff,      k = k0 + kk + 16; if (f < NFRAMES && k < NBINS) out[(ob + f) * NBINS + k] = r01; }
    { int f = f0 + ff + 16, k = k0 + kk;      if (f < NFRAMES && k < NBINS) out[(ob + f) * NBINS + k] = r10; }
    { int f = f0 + ff + 16, k = k0 + kk + 16; if (f < NFRAMES && k < NBINS) out[(ob + f) * NBINS + k] = r11; }
}

extern "C" void kernel_launch(void* const* d_in, const int* in_sizes, int n_in,
                              void* d_out, int out_size, void* d_ws, size_t ws_size,
                              hipStream_t stream) {
    const float* sig = (const float*)d_in[0];
    const float* win = (const float*)d_in[1];
    float* out = (float*)d_out;

    if (ws_size >= WS_NEED) {
        __bf16* wfr    = (__bf16*)d_ws;
        __bf16* sigb16 = (__bf16*)((char*)d_ws + SIG_OFF);
        convert_sig_kernel<<<dim3((NB * NT / 4 + 255) / 256), dim3(256), 0, stream>>>(sig, sigb16);
        build_wfrag_kernel<<<dim3((NKS * NKT * 64 + 255) / 256), dim3(256), 0, stream>>>(win, wfr);
        dim3 grid(GX, GY, NB);   // 7 x 19 x 16 = 2128 blocks
        stft_mfma_kernel<<<grid, dim3(256), 0, stream>>>(sigb16, wfr, out);
    } else {
        dim3 grid((NBINS + BKT - 1) / BKT, (NFRAMES + BFT - 1) / BFT, NB);
        stft_f32_kernel<<<grid, dim3(256), 0, stream>>>(sig, win, out);
    }
}